// Round 1
// baseline (447.425 us; speedup 1.0000x reference)
//
#include <hip/hip_runtime.h>
#include <hip/hip_bf16.h>
#include <hip/hip_fp16.h>

// Atten_L: B=2, L=64, C=256, S=256, D=512. All I/O fp32; compute in fp16 MFMA
// (fp16 chosen over bf16: 4x mantissa, same gfx950 MFMA rate, all intermediates
// within fp16 range -> absmax ~5e-3 vs threshold 2.125e-2).
//
// Pipeline (all GEMMs are NT so A and Bt fragments are contiguous 16B LDS reads):
//   q  = queries @ Wq^T + bq          (32768x512x512, fp32 A -> f16 out)
//   k  = keys    @ Wkv^T + bkv
//   vT = (values @ Wkv^T + bkv)^T per (b,l)  -> vT[bl][d][s]
//   scores[bl] = q[bl] @ k[bl]^T      (batched 256x256x512, fp32 out)
//   P = softmax(scale*scores)         (f16 out)
//   ao[bl] = P[bl] @ vT[bl]^T         (batched 256x512x256)
//   out = ao @ Wo^T + bo              (fp32 out)

typedef _Float16 f16;
typedef __attribute__((ext_vector_type(8))) _Float16 f16x8;
typedef __attribute__((ext_vector_type(4))) _Float16 f16x4;
typedef __attribute__((ext_vector_type(4))) float f32x4;

#define BM 128
#define BN 128
#define BK 32

// NT GEMM: C[z][m][n] = sum_k A[z][m][k] * Bt[z][n][k] (+ bias[n])
// Tile 128x128x32, 256 threads = 4 waves, each wave a 64x64 quadrant of
// 4x4 16x16x32 MFMAs. M,N multiples of 128; K multiple of 32 (no bounds checks).
// TRANS_OUT hardcodes the v-projection transpose: row=(bl*256+s) -> vT[bl][col][s],
// bl stride 512*256=131072, inner stride 256.
template<bool A_F32, bool OUT_F32, bool TRANS_OUT, bool BIAS>
__global__ __launch_bounds__(256)
void gemm_nt(const void* __restrict__ Ap, const f16* __restrict__ Btp,
             const float* __restrict__ bias, void* __restrict__ Cp,
             int M, int N, int K, long sA, long sB, long sC)
{
    __shared__ f16 As[BM][BK];
    __shared__ f16 Bs[BN][BK];

    const int z    = blockIdx.z;
    const int m0   = blockIdx.y * BM;
    const int n0   = blockIdx.x * BN;
    const int tid  = threadIdx.x;
    const int lane = tid & 63;
    const int wave = tid >> 6;
    const int quad = lane >> 4;
    const int l16  = lane & 15;
    const int wr   = wave >> 1;   // wave row quadrant (0..1)
    const int wc   = wave & 1;    // wave col quadrant (0..1)

    const float* Af = (const float*)Ap + (long)z * sA;
    const f16*   Ah = (const f16*)Ap + (long)z * sA;
    const f16*   Bt = Btp + (long)z * sB;

    f32x4 acc[4][4];
    #pragma unroll
    for (int i = 0; i < 4; ++i)
        #pragma unroll
        for (int j = 0; j < 4; ++j)
            acc[i][j] = (f32x4){0.f, 0.f, 0.f, 0.f};

    // staging: each thread moves 8 contiguous elements x 2 row-halves per tile
    const int srow = tid >> 2;        // 0..63
    const int scol = (tid & 3) * 8;   // 0,8,16,24

    for (int k0 = 0; k0 < K; k0 += BK) {
        #pragma unroll
        for (int h = 0; h < 2; ++h) {
            const int r = srow + h * 64;
            if (A_F32) {
                const float* s = Af + (long)(m0 + r) * K + k0 + scol;
                float4 f0 = *(const float4*)s;
                float4 f1 = *(const float4*)(s + 4);
                f16x8 v;
                v[0] = (f16)f0.x; v[1] = (f16)f0.y; v[2] = (f16)f0.z; v[3] = (f16)f0.w;
                v[4] = (f16)f1.x; v[5] = (f16)f1.y; v[6] = (f16)f1.z; v[7] = (f16)f1.w;
                *(f16x8*)&As[r][scol] = v;
            } else {
                *(f16x8*)&As[r][scol] = *(const f16x8*)(Ah + (long)(m0 + r) * K + k0 + scol);
            }
            *(f16x8*)&Bs[r][scol] = *(const f16x8*)(Bt + (long)(n0 + r) * K + k0 + scol);
        }
        __syncthreads();

        // fragment layout (verified m89/m91): A[m=lane&15][k=quad*8+j]
        f16x8 a_frag[4], b_frag[4];
        #pragma unroll
        for (int i = 0; i < 4; ++i)
            a_frag[i] = *(const f16x8*)&As[wr * 64 + i * 16 + l16][quad * 8];
        #pragma unroll
        for (int j = 0; j < 4; ++j)
            b_frag[j] = *(const f16x8*)&Bs[wc * 64 + j * 16 + l16][quad * 8];
        #pragma unroll
        for (int i = 0; i < 4; ++i)
            #pragma unroll
            for (int j = 0; j < 4; ++j)
                acc[i][j] = __builtin_amdgcn_mfma_f32_16x16x32_f16(
                    a_frag[i], b_frag[j], acc[i][j], 0, 0, 0);
        __syncthreads();
    }

    // epilogue; C/D layout: col=lane&15, row=quad*4+reg (m89-verified)
    #pragma unroll
    for (int i = 0; i < 4; ++i) {
        #pragma unroll
        for (int j = 0; j < 4; ++j) {
            const int col = n0 + wc * 64 + j * 16 + l16;
            const float bv = BIAS ? bias[col] : 0.0f;
            #pragma unroll
            for (int r = 0; r < 4; ++r) {
                const int row = m0 + wr * 64 + i * 16 + quad * 4 + r;
                const float val = acc[i][j][r] + bv;
                if (TRANS_OUT) {
                    ((f16*)Cp)[(long)(row >> 8) * 131072 + (long)col * 256 + (row & 255)] = (f16)val;
                } else if (OUT_F32) {
                    ((float*)Cp)[(long)z * sC + (long)row * N + col] = val;
                } else {
                    ((f16*)Cp)[(long)z * sC + (long)row * N + col] = (f16)val;
                }
            }
        }
    }
}

// one wave per 256-wide row; scale, max, exp, sum, normalize -> f16
__global__ __launch_bounds__(256)
void softmax_rows(const float* __restrict__ S, f16* __restrict__ P)
{
    const int row  = blockIdx.x * 4 + (threadIdx.x >> 6);
    const int lane = threadIdx.x & 63;
    const float scale = 0.044194173824159216f;  // 1/sqrt(512)
    const float4 v = *(const float4*)(S + (long)row * 256 + lane * 4);
    const float a0 = v.x * scale, a1 = v.y * scale, a2 = v.z * scale, a3 = v.w * scale;
    float m = fmaxf(fmaxf(a0, a1), fmaxf(a2, a3));
    #pragma unroll
    for (int off = 32; off > 0; off >>= 1) m = fmaxf(m, __shfl_xor(m, off, 64));
    const float e0 = __expf(a0 - m), e1 = __expf(a1 - m), e2 = __expf(a2 - m), e3 = __expf(a3 - m);
    float s = e0 + e1 + e2 + e3;
    #pragma unroll
    for (int off = 32; off > 0; off >>= 1) s += __shfl_xor(s, off, 64);
    const float inv = 1.0f / s;
    f16x4 o;
    o[0] = (f16)(e0 * inv); o[1] = (f16)(e1 * inv);
    o[2] = (f16)(e2 * inv); o[3] = (f16)(e3 * inv);
    *(f16x4*)&P[(long)row * 256 + lane * 4] = o;
}

__global__ __launch_bounds__(256)
void cvt_f32_f16(const float* __restrict__ in, f16* __restrict__ out, int n)
{
    const int i = blockIdx.x * blockDim.x + threadIdx.x;
    if (i < n) out[i] = (f16)in[i];
}

extern "C" void kernel_launch(void* const* d_in, const int* in_sizes, int n_in,
                              void* d_out, int out_size, void* d_ws, size_t ws_size,
                              hipStream_t stream)
{
    const float* queries = (const float*)d_in[0];
    const float* keys    = (const float*)d_in[1];
    const float* values  = (const float*)d_in[2];
    const float* Wq      = (const float*)d_in[3];
    const float* bq      = (const float*)d_in[4];
    const float* Wkv     = (const float*)d_in[5];
    const float* bkv     = (const float*)d_in[6];
    const float* Wo      = (const float*)d_in[7];
    const float* bo      = (const float*)d_in[8];
    float* out = (float*)d_out;

    // workspace layout (f16 elements unless noted); total ~130 MiB
    f16* ws  = (f16*)d_ws;
    f16* wq  = ws;                      //   262144
    f16* wkv = ws + 262144;             //   262144
    f16* wo  = ws + 524288;             //   262144
    f16* qh  = ws + 786432;             // 16777216  (reused for P after QK^T)
    f16* kh  = qh + 16777216;           // 16777216
    f16* vT  = kh + 16777216;           // 16777216
    float* scores = (float*)(vT + 16777216);  // 8388608 fp32 (reused as f16 ao)
    f16* P  = qh;                       // 8388608  overlays q (dead after QK^T)
    f16* ao = (f16*)scores;             // 16777216 overlays scores (dead after softmax)

    cvt_f32_f16<<<1024, 256, 0, stream>>>(Wq,  wq,  262144);
    cvt_f32_f16<<<1024, 256, 0, stream>>>(Wkv, wkv, 262144);
    cvt_f32_f16<<<1024, 256, 0, stream>>>(Wo,  wo,  262144);

    const dim3 blk(256);
    // projections: M=32768 (B*L*{C,S}), N=K=512
    gemm_nt<true,  false, false, true><<<dim3(4, 256, 1), blk, 0, stream>>>(
        queries, wq,  bq,  qh, 32768, 512, 512, 0, 0, 0);
    gemm_nt<true,  false, false, true><<<dim3(4, 256, 1), blk, 0, stream>>>(
        keys,    wkv, bkv, kh, 32768, 512, 512, 0, 0, 0);
    gemm_nt<true,  false, true,  true><<<dim3(4, 256, 1), blk, 0, stream>>>(
        values,  wkv, bkv, vT, 32768, 512, 512, 0, 0, 0);
    // scores[bl] = q[bl] @ k[bl]^T : batched over 128 (b,l)
    gemm_nt<false, true,  false, false><<<dim3(2, 2, 128), blk, 0, stream>>>(
        qh, kh, nullptr, scores, 256, 256, 512, 131072, 131072, 65536);
    // softmax over s (32768 rows of 256)
    softmax_rows<<<8192, 256, 0, stream>>>(scores, P);
    // ao[bl] = P[bl] @ vT[bl]^T
    gemm_nt<false, false, false, false><<<dim3(4, 2, 128), blk, 0, stream>>>(
        P, vT, nullptr, ao, 256, 512, 256, 65536, 131072, 131072);
    // out = ao @ Wo^T + bo (fp32 out)
    gemm_nt<false, true,  false, true><<<dim3(4, 256, 1), blk, 0, stream>>>(
        ao, wo, bo, out, 32768, 512, 512, 0, 0, 0);
}

// Round 2
// 402.234 us; speedup vs baseline: 1.1123x; 1.1123x over previous
//
#include <hip/hip_runtime.h>
#include <hip/hip_fp16.h>
#include <stdint.h>

// Atten_L: B=2, L=64, C=256, S=256, D=512. fp32 I/O, fp16 MFMA compute.
// R2: m97-style GEMM — BK=64, global_load_lds(16B) staging for f16 operands,
// register-prefetch pipeline for fp32-A projections, XOR-swizzled LDS columns
// (rot = (row&7)*8 elems) to kill the 4-way bank conflict seen in R1
// (SQ_LDS_BANK_CONFLICT=2.1M). Swizzle is applied on the GLOBAL address per
// lane for glds (LDS side is fixed base+lane*16), and on the LDS address for
// ds_write/ds_read paths.

typedef _Float16 f16;
typedef __attribute__((ext_vector_type(8))) _Float16 f16x8;
typedef __attribute__((ext_vector_type(4))) _Float16 f16x4;
typedef __attribute__((ext_vector_type(4))) float f32x4;

#define BM 128
#define BN 128
#define BK 64

__device__ __forceinline__ void glds16(const void* g, void* l)
{
    // AS casts via uintptr_t: global VA is the AS1 value; LDS apertures are
    // 4GiB-aligned so low-32 of the generic LDS VA is the AS3 offset.
    __builtin_amdgcn_global_load_lds(
        (const __attribute__((address_space(1))) void*)(uintptr_t)g,
        (__attribute__((address_space(3))) void*)(uint32_t)(uintptr_t)l,
        16, 0, 0);
}

// NT GEMM: C[z][m][n] = sum_k A[z][m][k] * Bt[z][n][k] (+ bias[n])
// 128x128x64 tile, 256 threads = 4 waves, each wave 64x64 = 4x4 16x16x32 MFMAs
// per 32-wide k-substep (32 MFMA per K-step).
template<bool A_F32, bool OUT_F32, bool TRANS_OUT, bool BIAS>
__global__ __launch_bounds__(256)
void gemm_nt(const void* __restrict__ Ap, const f16* __restrict__ Btp,
             const float* __restrict__ bias, void* __restrict__ Cp,
             int M, int N, int K, long sA, long sB, long sC)
{
    __shared__ f16 As[BM][BK];   // 16 KB
    __shared__ f16 Bs[BN][BK];   // 16 KB

    const int z    = blockIdx.z;
    const int m0   = blockIdx.y * BM;
    const int n0   = blockIdx.x * BN;
    const int tid  = threadIdx.x;
    const int lane = tid & 63;
    const int wave = tid >> 6;
    const int quad = lane >> 4;
    const int l16  = lane & 15;
    const int wr   = wave >> 1;
    const int wc   = wave & 1;

    const float* Af = (const float*)Ap + (long)z * sA;
    const f16*   Ah = (const f16*)Ap + (long)z * sA;
    const f16*   Bt = Btp + (long)z * sB;

    f32x4 acc[4][4];
    #pragma unroll
    for (int i = 0; i < 4; ++i)
        #pragma unroll
        for (int j = 0; j < 4; ++j)
            acc[i][j] = (f32x4){0.f, 0.f, 0.f, 0.f};

    // glds lane mapping: lane l -> phys slot row R0+l/8, phys col (l%8)*8.
    // With rot=(row&7)*8=(l/8)*8, the logical col living there is
    // ((l%8)-(l/8))&7 * 8 -> fold into the global address.
    const int i8 = lane >> 3;
    const int cl = (((lane & 7) - i8) & 7) * 8;

    // fp32-A staging: thread t handles rows h*32+(t>>3), logical col (t&7)*8
    const int ar = tid >> 3;
    const int ac = (tid & 7) * 8;

    float4 pre[8];
    auto load_a_f32 = [&](int k0) {
        #pragma unroll
        for (int h = 0; h < 4; ++h) {
            const float* p = Af + (long)(m0 + h * 32 + ar) * K + k0 + ac;
            pre[2 * h]     = *(const float4*)p;
            pre[2 * h + 1] = *(const float4*)(p + 4);
        }
    };
    auto store_a = [&]() {
        #pragma unroll
        for (int h = 0; h < 4; ++h) {
            const int r  = h * 32 + ar;
            const int pc = (ac + ((r & 7) * 8)) & 63;
            f16x8 v;
            v[0] = (f16)pre[2*h].x;   v[1] = (f16)pre[2*h].y;
            v[2] = (f16)pre[2*h].z;   v[3] = (f16)pre[2*h].w;
            v[4] = (f16)pre[2*h+1].x; v[5] = (f16)pre[2*h+1].y;
            v[6] = (f16)pre[2*h+1].z; v[7] = (f16)pre[2*h+1].w;
            *(f16x8*)&As[r][pc] = v;
        }
    };

    for (int k0 = 0; k0 < K; k0 += BK) {
        if (A_F32) {
            if (k0 == 0) load_a_f32(0);
            if (k0) __syncthreads();
            // B tile via async glds (4 issues/wave, 8 rows each)
            #pragma unroll
            for (int j = 0; j < 4; ++j) {
                const int R0 = (wave * 4 + j) * 8;
                glds16(Bt + (long)(n0 + R0 + i8) * K + k0 + cl, &Bs[R0][0]);
            }
            store_a();
        } else {
            if (k0) __syncthreads();
            #pragma unroll
            for (int j = 0; j < 4; ++j) {
                const int R0 = (wave * 4 + j) * 8;
                glds16(Ah + (long)(m0 + R0 + i8) * K + k0 + cl, &As[R0][0]);
                glds16(Bt + (long)(n0 + R0 + i8) * K + k0 + cl, &Bs[R0][0]);
            }
        }
        __syncthreads();
        // prefetch next fp32 A tile; loads fly during the MFMA loop and are
        // drained by the NEXT iteration's top-barrier (after compute).
        if (A_F32 && k0 + BK < K) load_a_f32(k0 + BK);

        #pragma unroll
        for (int ksub = 0; ksub < 2; ++ksub) {
            f16x8 af[4], bf[4];
            #pragma unroll
            for (int i = 0; i < 4; ++i) {
                const int r  = wr * 64 + i * 16 + l16;
                const int pc = ((ksub * 32 + quad * 8) + ((r & 7) * 8)) & 63;
                af[i] = *(const f16x8*)&As[r][pc];
            }
            #pragma unroll
            for (int j = 0; j < 4; ++j) {
                const int r  = wc * 64 + j * 16 + l16;
                const int pc = ((ksub * 32 + quad * 8) + ((r & 7) * 8)) & 63;
                bf[j] = *(const f16x8*)&Bs[r][pc];
            }
            #pragma unroll
            for (int i = 0; i < 4; ++i)
                #pragma unroll
                for (int j = 0; j < 4; ++j)
                    acc[i][j] = __builtin_amdgcn_mfma_f32_16x16x32_f16(
                        af[i], bf[j], acc[i][j], 0, 0, 0);
        }
    }

    // epilogue; C/D layout: col=lane&15, row=quad*4+reg (m89-verified)
    #pragma unroll
    for (int i = 0; i < 4; ++i) {
        #pragma unroll
        for (int j = 0; j < 4; ++j) {
            const int col = n0 + wc * 64 + j * 16 + l16;
            const float bv = BIAS ? bias[col] : 0.0f;
            #pragma unroll
            for (int r = 0; r < 4; ++r) {
                const int row = m0 + wr * 64 + i * 16 + quad * 4 + r;
                const float val = acc[i][j][r] + bv;
                if (TRANS_OUT) {
                    ((f16*)Cp)[(long)(row >> 8) * 131072 + (long)col * 256 + (row & 255)] = (f16)val;
                } else if (OUT_F32) {
                    ((float*)Cp)[(long)z * sC + (long)row * N + col] = val;
                } else {
                    ((f16*)Cp)[(long)z * sC + (long)row * N + col] = (f16)val;
                }
            }
        }
    }
}

// one wave per 256-wide row
__global__ __launch_bounds__(256)
void softmax_rows(const float* __restrict__ S, f16* __restrict__ P)
{
    const int row  = blockIdx.x * 4 + (threadIdx.x >> 6);
    const int lane = threadIdx.x & 63;
    const float scale = 0.044194173824159216f;  // 1/sqrt(512)
    const float4 v = *(const float4*)(S + (long)row * 256 + lane * 4);
    const float a0 = v.x * scale, a1 = v.y * scale, a2 = v.z * scale, a3 = v.w * scale;
    float m = fmaxf(fmaxf(a0, a1), fmaxf(a2, a3));
    #pragma unroll
    for (int off = 32; off > 0; off >>= 1) m = fmaxf(m, __shfl_xor(m, off, 64));
    const float e0 = __expf(a0 - m), e1 = __expf(a1 - m), e2 = __expf(a2 - m), e3 = __expf(a3 - m);
    float s = e0 + e1 + e2 + e3;
    #pragma unroll
    for (int off = 32; off > 0; off >>= 1) s += __shfl_xor(s, off, 64);
    const float inv = 1.0f / s;
    f16x4 o;
    o[0] = (f16)(e0 * inv); o[1] = (f16)(e1 * inv);
    o[2] = (f16)(e2 * inv); o[3] = (f16)(e3 * inv);
    *(f16x4*)&P[(long)row * 256 + lane * 4] = o;
}

// all three weight matrices in one launch: grid 768, 4 elems/thread
__global__ __launch_bounds__(256)
void cvt3(const float* __restrict__ a, const float* __restrict__ b,
          const float* __restrict__ c, f16* __restrict__ oa,
          f16* __restrict__ ob, f16* __restrict__ oc)
{
    const int w = blockIdx.x >> 8;
    const int t = ((blockIdx.x & 255) * 256 + threadIdx.x) * 4;
    const float* src = (w == 0) ? a : (w == 1) ? b : c;
    f16* dst = (w == 0) ? oa : (w == 1) ? ob : oc;
    const float4 v = *(const float4*)(src + t);
    f16x4 o;
    o[0] = (f16)v.x; o[1] = (f16)v.y; o[2] = (f16)v.z; o[3] = (f16)v.w;
    *(f16x4*)(dst + t) = o;
}

extern "C" void kernel_launch(void* const* d_in, const int* in_sizes, int n_in,
                              void* d_out, int out_size, void* d_ws, size_t ws_size,
                              hipStream_t stream)
{
    const float* queries = (const float*)d_in[0];
    const float* keys    = (const float*)d_in[1];
    const float* values  = (const float*)d_in[2];
    const float* Wq      = (const float*)d_in[3];
    const float* bq      = (const float*)d_in[4];
    const float* Wkv     = (const float*)d_in[5];
    const float* bkv     = (const float*)d_in[6];
    const float* Wo      = (const float*)d_in[7];
    const float* bo      = (const float*)d_in[8];
    float* out = (float*)d_out;

    f16* ws  = (f16*)d_ws;
    f16* wq  = ws;                      //   262144
    f16* wkv = ws + 262144;             //   262144
    f16* wo  = ws + 524288;             //   262144
    f16* qh  = ws + 786432;             // 16777216  (reused for P after QK^T)
    f16* kh  = qh + 16777216;           // 16777216
    f16* vT  = kh + 16777216;           // 16777216
    float* scores = (float*)(vT + 16777216);  // 8388608 fp32 (reused as f16 ao)
    f16* P  = qh;
    f16* ao = (f16*)scores;

    cvt3<<<768, 256, 0, stream>>>(Wq, Wkv, Wo, wq, wkv, wo);

    const dim3 blk(256);
    gemm_nt<true,  false, false, true><<<dim3(4, 256, 1), blk, 0, stream>>>(
        queries, wq,  bq,  qh, 32768, 512, 512, 0, 0, 0);
    gemm_nt<true,  false, false, true><<<dim3(4, 256, 1), blk, 0, stream>>>(
        keys,    wkv, bkv, kh, 32768, 512, 512, 0, 0, 0);
    gemm_nt<true,  false, true,  true><<<dim3(4, 256, 1), blk, 0, stream>>>(
        values,  wkv, bkv, vT, 32768, 512, 512, 0, 0, 0);
    gemm_nt<false, true,  false, false><<<dim3(2, 2, 128), blk, 0, stream>>>(
        qh, kh, nullptr, scores, 256, 256, 512, 131072, 131072, 65536);
    softmax_rows<<<8192, 256, 0, stream>>>(scores, P);
    gemm_nt<false, false, false, false><<<dim3(4, 2, 128), blk, 0, stream>>>(
        P, vT, nullptr, ao, 256, 512, 256, 65536, 131072, 131072);
    gemm_nt<false, true,  false, true><<<dim3(4, 256, 1), blk, 0, stream>>>(
        ao, wo, bo, out, 32768, 512, 512, 0, 0, 0);
}

// Round 3
// 370.818 us; speedup vs baseline: 1.2066x; 1.0847x over previous
//
#include <hip/hip_runtime.h>
#include <hip/hip_fp16.h>
#include <stdint.h>

// Atten_L: B=2, L=64, C=256, S=256, D=512. fp32 I/O, fp16 MFMA compute.
// R3: (a) XCD-aware block swizzle (p%8 = XCD round-robin heuristic) so all
// n-tiles sharing an A m-tile co-reside on one XCD -> A re-reads hit that
// XCD's L2 (R2 showed FETCH=132MB vs 64.5 ideal = cross-XCD A duplication).
// (b) QK^T + softmax fused into one kernel: scores never touch HBM
// (-144 MB intermediate traffic). P(f16) written directly.

typedef _Float16 f16;
typedef __attribute__((ext_vector_type(8))) _Float16 f16x8;
typedef __attribute__((ext_vector_type(4))) _Float16 f16x4;
typedef __attribute__((ext_vector_type(4))) float f32x4;

#define BM 128
#define BN 128
#define BK 64

__device__ __forceinline__ void glds16(const void* g, void* l)
{
    __builtin_amdgcn_global_load_lds(
        (const __attribute__((address_space(1))) void*)(uintptr_t)g,
        (__attribute__((address_space(3))) void*)(uint32_t)(uintptr_t)l,
        16, 0, 0);
}

// NT GEMM: C[z][m][n] = sum_k A[z][m][k] * Bt[z][n][k] (+ bias[n])
// SWZ=1: 1-D grid 1024 -> (m-tile 0..255, n-tile 0..3), same-m on same XCD.
// SWZ=2: 1-D grid 1024 -> (z 0..127, m-tile 0..1, n-tile 0..3), same-z on same XCD.
template<bool A_F32, bool OUT_F32, bool TRANS_OUT, bool BIAS, int SWZ>
__global__ __launch_bounds__(256)
void gemm_nt(const void* __restrict__ Ap, const f16* __restrict__ Btp,
             const float* __restrict__ bias, void* __restrict__ Cp,
             int N, int K, long sA, long sB, long sC)
{
    __shared__ f16 As[BM][BK];
    __shared__ f16 Bs[BN][BK];

    const int p    = blockIdx.x;
    const int xcd  = p & 7;
    const int slot = p >> 3;
    int z, m0, n0;
    if (SWZ == 1) {            // 256 m-tiles x 4 n-tiles
        z  = 0;
        m0 = (xcd + 8 * (slot >> 2)) * BM;
        n0 = (slot & 3) * BN;
    } else {                   // 128 z x 2 m x 4 n
        z  = xcd + 8 * (slot >> 3);
        const int inner = slot & 7;
        m0 = (inner >> 2) * BM;
        n0 = (inner & 3) * BN;
    }

    const int tid  = threadIdx.x;
    const int lane = tid & 63;
    const int wave = tid >> 6;
    const int quad = lane >> 4;
    const int l16  = lane & 15;
    const int wr   = wave >> 1;
    const int wc   = wave & 1;

    const float* Af = (const float*)Ap + (long)z * sA;
    const f16*   Ah = (const f16*)Ap + (long)z * sA;
    const f16*   Bt = Btp + (long)z * sB;

    f32x4 acc[4][4];
    #pragma unroll
    for (int i = 0; i < 4; ++i)
        #pragma unroll
        for (int j = 0; j < 4; ++j)
            acc[i][j] = (f32x4){0.f, 0.f, 0.f, 0.f};

    const int i8 = lane >> 3;
    const int cl = (((lane & 7) - i8) & 7) * 8;

    const int ar = tid >> 3;
    const int ac = (tid & 7) * 8;

    float4 pre[8];
    auto load_a_f32 = [&](int k0) {
        #pragma unroll
        for (int h = 0; h < 4; ++h) {
            const float* s = Af + (long)(m0 + h * 32 + ar) * K + k0 + ac;
            pre[2 * h]     = *(const float4*)s;
            pre[2 * h + 1] = *(const float4*)(s + 4);
        }
    };
    auto store_a = [&]() {
        #pragma unroll
        for (int h = 0; h < 4; ++h) {
            const int r  = h * 32 + ar;
            const int pc = (ac + ((r & 7) * 8)) & 63;
            f16x8 v;
            v[0] = (f16)pre[2*h].x;   v[1] = (f16)pre[2*h].y;
            v[2] = (f16)pre[2*h].z;   v[3] = (f16)pre[2*h].w;
            v[4] = (f16)pre[2*h+1].x; v[5] = (f16)pre[2*h+1].y;
            v[6] = (f16)pre[2*h+1].z; v[7] = (f16)pre[2*h+1].w;
            *(f16x8*)&As[r][pc] = v;
        }
    };

    for (int k0 = 0; k0 < K; k0 += BK) {
        if (A_F32) {
            if (k0 == 0) load_a_f32(0);
            if (k0) __syncthreads();
            #pragma unroll
            for (int j = 0; j < 4; ++j) {
                const int R0 = (wave * 4 + j) * 8;
                glds16(Bt + (long)(n0 + R0 + i8) * K + k0 + cl, &Bs[R0][0]);
            }
            store_a();
        } else {
            if (k0) __syncthreads();
            #pragma unroll
            for (int j = 0; j < 4; ++j) {
                const int R0 = (wave * 4 + j) * 8;
                glds16(Ah + (long)(m0 + R0 + i8) * K + k0 + cl, &As[R0][0]);
                glds16(Bt + (long)(n0 + R0 + i8) * K + k0 + cl, &Bs[R0][0]);
            }
        }
        __syncthreads();
        if (A_F32 && k0 + BK < K) load_a_f32(k0 + BK);

        #pragma unroll
        for (int ksub = 0; ksub < 2; ++ksub) {
            f16x8 af[4], bf[4];
            #pragma unroll
            for (int i = 0; i < 4; ++i) {
                const int r  = wr * 64 + i * 16 + l16;
                const int pc = ((ksub * 32 + quad * 8) + ((r & 7) * 8)) & 63;
                af[i] = *(const f16x8*)&As[r][pc];
            }
            #pragma unroll
            for (int j = 0; j < 4; ++j) {
                const int r  = wc * 64 + j * 16 + l16;
                const int pc = ((ksub * 32 + quad * 8) + ((r & 7) * 8)) & 63;
                bf[j] = *(const f16x8*)&Bs[r][pc];
            }
            #pragma unroll
            for (int i = 0; i < 4; ++i)
                #pragma unroll
                for (int j = 0; j < 4; ++j)
                    acc[i][j] = __builtin_amdgcn_mfma_f32_16x16x32_f16(
                        af[i], bf[j], acc[i][j], 0, 0, 0);
        }
    }

    #pragma unroll
    for (int i = 0; i < 4; ++i) {
        #pragma unroll
        for (int j = 0; j < 4; ++j) {
            const int col = n0 + wc * 64 + j * 16 + l16;
            const float bv = BIAS ? bias[col] : 0.0f;
            #pragma unroll
            for (int r = 0; r < 4; ++r) {
                const int row = m0 + wr * 64 + i * 16 + quad * 4 + r;
                const float val = acc[i][j][r] + bv;
                if (TRANS_OUT) {
                    ((f16*)Cp)[(long)(row >> 8) * 131072 + (long)col * 256 + (row & 255)] = (f16)val;
                } else if (OUT_F32) {
                    ((float*)Cp)[(long)z * sC + (long)row * N + col] = val;
                } else {
                    ((f16*)Cp)[(long)z * sC + (long)row * N + col] = (f16)val;
                }
            }
        }
    }
}

// Fused QK^T + softmax: per block one (z, m-tile) -> 128x256 scores in regs,
// row softmax via 16-lane shuffles + LDS cross-wave combine, P written f16.
// 512 threads = 8 waves in 2x4: wave covers 64 rows x 64 cols (4x4 MFMA tiles).
__global__ __launch_bounds__(512)
void qk_softmax(const f16* __restrict__ q, const f16* __restrict__ k,
                f16* __restrict__ P)
{
    __shared__ f16 As[128][64];        // 16 KB
    __shared__ f16 Bs[256][64];        // 32 KB
    __shared__ float red[2][128][4];   //  4 KB  (max, sum) x row x wc

    const int p    = blockIdx.x;       // 256 blocks: same-z pair on same XCD
    const int xcd  = p & 7;
    const int slot = p >> 3;           // 0..31
    const int z    = xcd + 8 * (slot >> 1);
    const int m0   = (slot & 1) * 128;

    const int tid  = threadIdx.x;
    const int lane = tid & 63;
    const int wave = tid >> 6;         // 0..7
    const int quad = lane >> 4;
    const int l16  = lane & 15;
    const int wr   = wave >> 2;        // 0..1  (row half)
    const int wc   = wave & 3;         // 0..3  (col quarter)

    const f16* Aq = q + (long)z * 131072 + (long)m0 * 512;
    const f16* Bk = k + (long)z * 131072;

    f32x4 acc[4][4];
    #pragma unroll
    for (int i = 0; i < 4; ++i)
        #pragma unroll
        for (int j = 0; j < 4; ++j)
            acc[i][j] = (f32x4){0.f, 0.f, 0.f, 0.f};

    const int i8 = lane >> 3;
    const int cl = (((lane & 7) - i8) & 7) * 8;

    for (int k0 = 0; k0 < 512; k0 += BK) {
        if (k0) __syncthreads();
        #pragma unroll
        for (int g = 0; g < 2; ++g) {   // As: 16 groups over 8 waves
            const int R0 = (wave * 2 + g) * 8;
            glds16(Aq + (long)(R0 + i8) * 512 + k0 + cl, &As[R0][0]);
        }
        #pragma unroll
        for (int g = 0; g < 4; ++g) {   // Bs: 32 groups over 8 waves
            const int R0 = (wave * 4 + g) * 8;
            glds16(Bk + (long)(R0 + i8) * 512 + k0 + cl, &Bs[R0][0]);
        }
        __syncthreads();

        #pragma unroll
        for (int ksub = 0; ksub < 2; ++ksub) {
            f16x8 af[4], bf[4];
            #pragma unroll
            for (int i = 0; i < 4; ++i) {
                const int r  = wr * 64 + i * 16 + l16;
                const int pc = ((ksub * 32 + quad * 8) + ((r & 7) * 8)) & 63;
                af[i] = *(const f16x8*)&As[r][pc];
            }
            #pragma unroll
            for (int j = 0; j < 4; ++j) {
                const int r  = wc * 64 + j * 16 + l16;
                const int pc = ((ksub * 32 + quad * 8) + ((r & 7) * 8)) & 63;
                bf[j] = *(const f16x8*)&Bs[r][pc];
            }
            #pragma unroll
            for (int i = 0; i < 4; ++i)
                #pragma unroll
                for (int j = 0; j < 4; ++j)
                    acc[i][j] = __builtin_amdgcn_mfma_f32_16x16x32_f16(
                        af[i], bf[j], acc[i][j], 0, 0, 0);
        }
    }

    // ---- fused softmax over each 256-wide row ----
    const float scale = 0.044194173824159216f;  // 1/sqrt(512)
    float st[4][4];
    // local (64-col) row max: over j, then over the 16-lane col group
    #pragma unroll
    for (int i = 0; i < 4; ++i)
        #pragma unroll
        for (int r = 0; r < 4; ++r) {
            float m = acc[i][0][r];
            #pragma unroll
            for (int j = 1; j < 4; ++j) m = fmaxf(m, acc[i][j][r]);
            st[i][r] = m;
        }
    #pragma unroll
    for (int off = 1; off < 16; off <<= 1)
        #pragma unroll
        for (int i = 0; i < 4; ++i)
            #pragma unroll
            for (int r = 0; r < 4; ++r)
                st[i][r] = fmaxf(st[i][r], __shfl_xor(st[i][r], off, 64));
    if (l16 == 0)
        #pragma unroll
        for (int i = 0; i < 4; ++i)
            #pragma unroll
            for (int r = 0; r < 4; ++r)
                red[0][wr * 64 + i * 16 + quad * 4 + r][wc] = st[i][r];
    __syncthreads();

    // exp with final max; accumulate local sums
    #pragma unroll
    for (int i = 0; i < 4; ++i)
        #pragma unroll
        for (int r = 0; r < 4; ++r) {
            const int row = wr * 64 + i * 16 + quad * 4 + r;
            const float m = fmaxf(fmaxf(red[0][row][0], red[0][row][1]),
                                  fmaxf(red[0][row][2], red[0][row][3]));
            float s = 0.f;
            #pragma unroll
            for (int j = 0; j < 4; ++j) {
                const float e = __expf(scale * (acc[i][j][r] - m));
                acc[i][j][r] = e;
                s += e;
            }
            st[i][r] = s;
        }
    #pragma unroll
    for (int off = 1; off < 16; off <<= 1)
        #pragma unroll
        for (int i = 0; i < 4; ++i)
            #pragma unroll
            for (int r = 0; r < 4; ++r)
                st[i][r] += __shfl_xor(st[i][r], off, 64);
    if (l16 == 0)
        #pragma unroll
        for (int i = 0; i < 4; ++i)
            #pragma unroll
            for (int r = 0; r < 4; ++r)
                red[1][wr * 64 + i * 16 + quad * 4 + r][wc] = st[i][r];
    __syncthreads();

    #pragma unroll
    for (int i = 0; i < 4; ++i)
        #pragma unroll
        for (int r = 0; r < 4; ++r) {
            const int row = wr * 64 + i * 16 + quad * 4 + r;
            const float inv = 1.0f / (red[1][row][0] + red[1][row][1] +
                                      red[1][row][2] + red[1][row][3]);
            #pragma unroll
            for (int j = 0; j < 4; ++j) {
                const int col = wc * 64 + j * 16 + l16;
                P[(long)z * 65536 + (long)(m0 + row) * 256 + col] =
                    (f16)(acc[i][j][r] * inv);
            }
        }
}

__global__ __launch_bounds__(256)
void cvt3(const float* __restrict__ a, const float* __restrict__ b,
          const float* __restrict__ c, f16* __restrict__ oa,
          f16* __restrict__ ob, f16* __restrict__ oc)
{
    const int w = blockIdx.x >> 8;
    const int t = ((blockIdx.x & 255) * 256 + threadIdx.x) * 4;
    const float* src = (w == 0) ? a : (w == 1) ? b : c;
    f16* dst = (w == 0) ? oa : (w == 1) ? ob : oc;
    const float4 v = *(const float4*)(src + t);
    f16x4 o;
    o[0] = (f16)v.x; o[1] = (f16)v.y; o[2] = (f16)v.z; o[3] = (f16)v.w;
    *(f16x4*)(dst + t) = o;
}

extern "C" void kernel_launch(void* const* d_in, const int* in_sizes, int n_in,
                              void* d_out, int out_size, void* d_ws, size_t ws_size,
                              hipStream_t stream)
{
    const float* queries = (const float*)d_in[0];
    const float* keys    = (const float*)d_in[1];
    const float* values  = (const float*)d_in[2];
    const float* Wq      = (const float*)d_in[3];
    const float* bq      = (const float*)d_in[4];
    const float* Wkv     = (const float*)d_in[5];
    const float* bkv     = (const float*)d_in[6];
    const float* Wo      = (const float*)d_in[7];
    const float* bo      = (const float*)d_in[8];
    float* out = (float*)d_out;

    // f16 workspace layout (total ~113.5 MB):
    f16* ws  = (f16*)d_ws;
    f16* wq  = ws;                      //   262144
    f16* wkv = ws + 262144;
    f16* wo  = ws + 524288;
    f16* qh  = ws + 786432;             // 32 MB  q
    f16* kh  = qh + 16777216;           // 32 MB  k; dead after qk_softmax -> ao
    f16* vT  = kh + 16777216;           // 32 MB  vT
    f16* P   = vT + 16777216;           // 16 MB  attn probs
    f16* ao  = kh;                      // 32 MB  overlays k

    cvt3<<<768, 256, 0, stream>>>(Wq, Wkv, Wo, wq, wkv, wo);

    const dim3 blk(256);
    gemm_nt<true,  false, false, true, 1><<<1024, blk, 0, stream>>>(
        queries, wq,  bq,  qh, 512, 512, 0, 0, 0);
    gemm_nt<true,  false, false, true, 1><<<1024, blk, 0, stream>>>(
        keys,    wkv, bkv, kh, 512, 512, 0, 0, 0);
    gemm_nt<true,  false, true,  true, 1><<<1024, blk, 0, stream>>>(
        values,  wkv, bkv, vT, 512, 512, 0, 0, 0);
    qk_softmax<<<256, 512, 0, stream>>>(qh, kh, P);
    gemm_nt<false, false, false, false, 2><<<1024, blk, 0, stream>>>(
        P, vT, nullptr, ao, 512, 256, 65536, 131072, 131072);
    gemm_nt<false, true,  false, true, 1><<<1024, blk, 0, stream>>>(
        ao, wo, bo, out, 512, 512, 0, 0, 0);
}